// Round 9
// baseline (481.680 us; speedup 1.0000x reference)
//
#include <hip/hip_runtime.h>

typedef float f32x4 __attribute__((ext_vector_type(4)));
typedef unsigned int uint32;
typedef unsigned long long uint64;

#define LPAD 1024   // staging capacity for a source column (L=400 fits)

// ---------------------------------------------------------------------------
// Prep (B blocks): per source column b
//   1. zero this column's global bitmap region (NWp words in d_ws)
//   2. rank-sort (v,l) ascending by (v,l) -> sv/sl  (O(L^2), ~2us total)
//   3. set bitmap bits for present vocab ids (atomicOr, device scope)
// Last-occurrence-wins falls out of upper_bound (max l sorts last per v).
// ---------------------------------------------------------------------------
__global__ __launch_bounds__(256) void prep_kernel(
    const int* __restrict__ sources, int* __restrict__ sv, int* __restrict__ sl,
    uint32* __restrict__ bmG, int L, int B, int V, int NWp)
{
    const int b = blockIdx.x;
    uint32* __restrict__ bmb = bmG + (size_t)b * NWp;
    for (int w = threadIdx.x; w < NWp; w += 256) bmb[w] = 0u;

    __shared__ int s_col[LPAD];
    for (int l = threadIdx.x; l < L; l += 256) {
        const int v = sources[(size_t)l * B + b];
        s_col[l] = (v >= 0 && v < V) ? v : 0x7FFFFFFF;   // mode="drop"
    }
    __syncthreads();

    int* __restrict__ svb = sv + (size_t)b * L;
    int* __restrict__ slb = sl + (size_t)b * L;
    for (int l = threadIdx.x; l < L; l += 256) {
        const int v = s_col[l];
        int rank = 0;
        for (int k = 0; k < L; ++k) {
            const int vk = s_col[k];
            rank += (vk < v) || (vk == v && k < l);
        }
        svb[rank] = v;
        slb[rank] = l;
        if (v < V) atomicOr(&bmb[v >> 5], 1u << (v & 31));
    }
}

// ---------------------------------------------------------------------------
// Fused single-pass, FLAT grid-stride mapping (copy-identical geometry):
// all in-flight waves touch one compact sliding address window, like the
// 6.3-6.8 TB/s copy/fill references — vs per-row blocks whose instantaneous
// footprint scatters across the whole matrix (R1-R8: pinned at ~3.6 TB/s).
// row = g/V via exact magic multiply; scatter test via L2-resident global
// bitmap; resolution via binary search in L2-hot sorted lists. No LDS.
// ---------------------------------------------------------------------------
__global__ __launch_bounds__(256) void fused_flat_kernel(
    const float* __restrict__ vd, const float* __restrict__ attns,
    const float* __restrict__ pgs, const int* __restrict__ sv,
    const int* __restrict__ sl, const uint32* __restrict__ bmG,
    float* __restrict__ out, int V, int L, int B, int NWp,
    uint64 magicM, long long n4, long long total)
{
    const long long stride = (long long)gridDim.x * 256;
    const uint32 bpow2 = ((B & (B - 1)) == 0);

    for (long long i4 = (long long)blockIdx.x * 256 + threadIdx.x;
         i4 < n4; i4 += stride) {
        const uint64 g0 = (uint64)i4 << 2;
        uint32 row = (uint32)((g0 * magicM) >> 48);
        uint32 j0  = (uint32)(g0 - (uint64)row * (uint32)V);
        f32x4 x = *(const f32x4*)(vd + g0);

        if (j0 + 4u <= (uint32)V) {                      // common: one row
            const float pg = pgs[row];
            x *= pg;
            const uint32 b = bpow2 ? (row & (uint32)(B - 1)) : (row % (uint32)B);
            const uint32* __restrict__ bmb = bmG + (size_t)b * NWp;
            const uint32 w = j0 >> 5, sh = j0 & 31u;
            uint32 bits = bmb[w] >> sh;
            if (sh > 28u) bits |= bmb[w + 1] << (32u - sh);
            bits &= 0xFu;
            if (bits) {
                const float gate = 1.0f - pg;
                const int* __restrict__ svb = sv + (size_t)b * L;
                const int* __restrict__ slb = sl + (size_t)b * L;
#pragma unroll
                for (int e = 0; e < 4; ++e)
                    if ((bits >> e) & 1u) {
                        const int j = (int)(j0 + e);
                        int lo = 0, hi = L;
                        while (lo < hi) {
                            const int mid = (lo + hi) >> 1;
                            if (svb[mid] <= j) lo = mid + 1; else hi = mid;
                        }
                        x[e] += gate * attns[(size_t)row * L + slb[lo - 1]];
                    }
            }
            __builtin_nontemporal_store(x, (f32x4*)(out + g0));
        } else {                                          // row-boundary vector
            f32x4 xo;
#pragma unroll
            for (int e = 0; e < 4; ++e) {
                uint32 re = row, je = j0 + e;
                if (je >= (uint32)V) { re = row + 1; je -= (uint32)V; }
                const float pg = pgs[re];
                float xe = x[e] * pg;
                const uint32 b = bpow2 ? (re & (uint32)(B - 1)) : (re % (uint32)B);
                const uint32* __restrict__ bmb = bmG + (size_t)b * NWp;
                if ((bmb[je >> 5] >> (je & 31u)) & 1u) {
                    const int* __restrict__ svb = sv + (size_t)b * L;
                    const int* __restrict__ slb = sl + (size_t)b * L;
                    int lo = 0, hi = L;
                    while (lo < hi) {
                        const int mid = (lo + hi) >> 1;
                        if (svb[mid] <= (int)je) lo = mid + 1; else hi = mid;
                    }
                    xe += (1.0f - pg) * attns[(size_t)re * L + slb[lo - 1]];
                }
                xo[e] = xe;
            }
            __builtin_nontemporal_store(xo, (f32x4*)(out + g0));
        }
    }

    // scalar tail if total % 4 != 0 (not hit for this problem's sizes)
    for (long long g = (n4 << 2) + (long long)blockIdx.x * 256 + threadIdx.x;
         g < total; g += stride) {
        const uint32 row = (uint32)(((uint64)g * magicM) >> 48);
        const uint32 j   = (uint32)((uint64)g - (uint64)row * (uint32)V);
        const float pg = pgs[row];
        float xe = pg * vd[g];
        const uint32 b = bpow2 ? (row & (uint32)(B - 1)) : (row % (uint32)B);
        const uint32* bmb = bmG + (size_t)b * NWp;
        if ((bmb[j >> 5] >> (j & 31u)) & 1u) {
            const int* svb = sv + (size_t)b * L;
            const int* slb = sl + (size_t)b * L;
            int lo = 0, hi = L;
            while (lo < hi) {
                const int mid = (lo + hi) >> 1;
                if (svb[mid] <= (int)j) lo = mid + 1; else hi = mid;
            }
            xe += (1.0f - pg) * attns[(size_t)row * L + slb[lo - 1]];
        }
        __builtin_nontemporal_store(xe, &out[g]);
    }
}

// ---------------------------------------------------------------------------
// Fallback (round-1 fused kernel, verified correct) if ws too small.
// ---------------------------------------------------------------------------
__global__ __launch_bounds__(256) void fused_fallback_kernel(
    const float* __restrict__ vocab_ds, const float* __restrict__ attns,
    const float* __restrict__ p_gens, const int* __restrict__ sources,
    float* __restrict__ out, int V, int L, int B)
{
    const int row = blockIdx.x;
    const int tid = threadIdx.x;
    const size_t base = (size_t)row * (size_t)V;
    const float pg = p_gens[row];

    const int mis  = (int)(base & 3);
    const int pre  = mis ? (4 - mis) : 0;
    const int preN = pre < V ? pre : V;
    for (int j = tid; j < preN; j += blockDim.x)
        out[base + j] = pg * vocab_ds[base + j];
    const int nvec = (V - preN) >> 2;
    const f32x4* __restrict__ v4 = (const f32x4*)(vocab_ds + base + preN);
    f32x4* __restrict__ o4       = (f32x4*)(out + base + preN);
    for (int i = tid; i < nvec; i += blockDim.x) {
        f32x4 x = v4[i];
        x *= pg;
        o4[i] = x;
    }
    for (int j = preN + (nvec << 2) + tid; j < V; j += blockDim.x)
        out[base + j] = pg * vocab_ds[base + j];

    __shared__ int s_src[512];
    const int b = row % B;
    const bool use_lds = (L <= 512);
    if (use_lds) {
        for (int l = tid; l < L; l += blockDim.x)
            s_src[l] = sources[(size_t)l * B + b];
    }
    __syncthreads();
    const float gate = 1.0f - pg;
    for (int l = tid; l < L; l += blockDim.x) {
        const int v = use_lds ? s_src[l] : sources[(size_t)l * B + b];
        if (v < 0 || v >= V) continue;
        bool last = true;
        for (int l2 = l + 1; l2 < L; ++l2) {
            const int v2 = use_lds ? s_src[l2] : sources[(size_t)l2 * B + b];
            if (v2 == v) { last = false; break; }
        }
        if (last) {
            const float a = gate * attns[(size_t)row * L + l];
            out[base + v] = pg * vocab_ds[base + v] + a;
        }
    }
}

extern "C" void kernel_launch(void* const* d_in, const int* in_sizes, int n_in,
                              void* d_out, int out_size, void* d_ws, size_t ws_size,
                              hipStream_t stream) {
    const float* vocab_ds = (const float*)d_in[0];
    const float* attns    = (const float*)d_in[1];
    const float* p_gens   = (const float*)d_in[2];
    const int*   sources  = (const int*)d_in[3];
    const int rows = in_sizes[2];
    const int V    = in_sizes[0] / rows;
    const int L    = in_sizes[1] / rows;
    const int B    = in_sizes[3] / L;
    float* out = (float*)d_out;

    const int NWp = ((V + 31) >> 5) + 1;   // +1 pad word for spanning reads
    const size_t need = (size_t)B * (size_t)L * 2 * sizeof(int)
                      + (size_t)B * (size_t)NWp * sizeof(uint32);
    const bool fits = (ws_size >= need) && (L <= LPAD);

    if (fits) {
        int*    sv  = (int*)d_ws;
        int*    sl  = sv + (size_t)B * (size_t)L;
        uint32* bmG = (uint32*)(sl + (size_t)B * (size_t)L);

        const long long total = (long long)rows * (long long)V;
        const long long n4    = total >> 2;
        const uint64 magicM =
            (uint64)((((__uint128_t)1) << 48) / (uint32)V) + 1ull;

        prep_kernel<<<B, 256, 0, stream>>>(sources, sv, sl, bmG, L, B, V, NWp);
        fused_flat_kernel<<<2048, 256, 0, stream>>>(
            vocab_ds, attns, p_gens, sv, sl, bmG, out,
            V, L, B, NWp, magicM, n4, total);
    } else {
        fused_fallback_kernel<<<rows, 256, 0, stream>>>(
            vocab_ds, attns, p_gens, sources, out, V, L, B);
    }
}

// Round 10
// 251.440 us; speedup vs baseline: 1.9157x; 1.9157x over previous
//
#include <hip/hip_runtime.h>

typedef float f32x4 __attribute__((ext_vector_type(4)));
typedef unsigned int uint32;

#define MAXV 51200            // bitmap capacity; V=50257 fits
#define NWMAX (MAXV / 32 + 1) // 1601 words (+1 pad for spanning reads)
#define LPAD 1024             // sorted-list capacity (L=400 fits)

// ---------------------------------------------------------------------------
// Prep: per source column b, sort (v, l) pairs ascending by (v, l) via O(L^2)
// rank sort. Row-independent (rows share columns mod B). Last-occurrence-wins
// falls out of upper_bound search later (max l sorts last among equal v).
// ---------------------------------------------------------------------------
__global__ __launch_bounds__(256) void sort_kernel(
    const int* __restrict__ sources, int* __restrict__ sv, int* __restrict__ sl,
    int L, int B, int V)
{
    const int b = blockIdx.x;
    __shared__ int s_col[LPAD];
    for (int l = threadIdx.x; l < L; l += 256) {
        const int v = sources[(size_t)l * B + b];
        s_col[l] = (v >= 0 && v < V) ? v : 0x7FFFFFFF;   // mode="drop"
    }
    __syncthreads();
    int* __restrict__ svb = sv + (size_t)b * L;
    int* __restrict__ slb = sl + (size_t)b * L;
    for (int l = threadIdx.x; l < L; l += 256) {
        const int v = s_col[l];
        int rank = 0;
        for (int k = 0; k < L; ++k) {
            const int vk = s_col[k];
            rank += (vk < v) || (vk == v && k < l);
        }
        svb[rank] = v;
        slb[rank] = l;
    }
}

// ---------------------------------------------------------------------------
// Fused single-pass (R6 structure) + asm-forced 8-deep load pipeline.
// Loads issued via volatile asm (no compiler auto-wait); consumption gated by
// explicit counted `s_waitcnt vmcnt(7)` + sched_barrier(0). In-order vmcnt
// retirement: >=7 VMEM ops are always newer than the awaited load, so
// vmcnt(7) guarantees its retirement while never draining the NT stores.
// ---------------------------------------------------------------------------
__global__ __launch_bounds__(256) void fused_kernel(
    const float* __restrict__ vd, const float* __restrict__ attns,
    const float* __restrict__ pgs, const int* __restrict__ sv,
    const int* __restrict__ sl, float* __restrict__ out, int V, int L, int B)
{
    const int row = blockIdx.x;
    const int tid = threadIdx.x;
    const int b   = row % B;

    __shared__ uint32 bm[NWMAX];
    __shared__ int    s_v[LPAD];
    __shared__ int    s_l[LPAD];
    __shared__ float  s_attn[LPAD];

    const int NW = (V + 31) >> 5;
    for (int w = tid; w < NW + 1; w += 256) bm[w] = 0u;
    const int* __restrict__ svb = sv + (size_t)b * L;
    const int* __restrict__ slb = sl + (size_t)b * L;
    for (int t = tid; t < LPAD; t += 256) {
        s_v[t]    = (t < L) ? svb[t] : 0x7FFFFFFF;
        s_l[t]    = (t < L) ? slb[t] : 0;
        s_attn[t] = (t < L) ? attns[(size_t)row * L + t] : 0.0f;
    }
    __syncthreads();
    for (int t = tid; t < L; t += 256) {
        const int v = s_v[t];
        if (v < V) atomicOr(&bm[v >> 5], 1u << (v & 31));
    }
    __syncthreads();

    const float pg   = pgs[row];
    const float gate = 1.0f - pg;
    const size_t base = (size_t)row * (size_t)V;

    // upper_bound(j) - 1 => last entry with s_v==j => max l => last-wins
    auto lookup = [&](int j) -> float {
        int lo = 0, hi = LPAD;
        while (lo < hi) {
            const int mid = (lo + hi) >> 1;
            if (s_v[mid] <= j) lo = mid + 1; else hi = mid;
        }
        return gate * s_attn[s_l[lo - 1]];
    };

    // peel to 16B alignment (V odd -> base mod 4 rotates per row)
    const int mis  = (int)(base & 3);
    const int pre  = mis ? (4 - mis) : 0;
    const int preN = pre < V ? pre : V;
    if (tid < preN) {
        const int j = tid;
        float x = pg * vd[base + j];
        if ((bm[j >> 5] >> (j & 31)) & 1u) x += lookup(j);
        __builtin_nontemporal_store(x, &out[base + j]);
    }

    const int nvec = (V - preN) >> 2;
    const f32x4* __restrict__ v4 = (const f32x4*)(vd + base + preN);
    f32x4* __restrict__ o4       = (f32x4*)(out + base + preN);

    // compute + NT-store one vector (value already in registers)
    auto finish = [&](f32x4 x, int i, f32x4* po) {
        x *= pg;
        const int j0 = preN + (i << 2);
        const int w  = j0 >> 5;
        const uint32 sh = (uint32)(j0 & 31);
        uint32 bits = bm[w] >> sh;
        if (sh > 28u) bits |= bm[w + 1] << (32u - sh);
        bits &= 0xFu;
        if (bits) {
#pragma unroll
            for (int e = 0; e < 4; ++e)
                if ((bits >> e) & 1u) x[e] += lookup(j0 + e);
        }
        __builtin_nontemporal_store(x, po);
    };

    const int nfull  = nvec >> 8;          // steps where all 256 lanes valid
    int nppipe = nfull & ~7;               // multiple of 8 for static slots

    if (nppipe >= 8) {
        const f32x4* pl = v4 + tid;        // load cursor (8 steps ahead)
        f32x4*       po = o4 + tid;        // store cursor
        int icur = tid;                    // consume vector index
        f32x4 x0, x1, x2, x3, x4_, x5, x6, x7;

#define LOADV(xx)                                                         \
        asm volatile("global_load_dwordx4 %0, %1, off"                    \
                     : "=&v"(xx) : "v"(pl) : "memory");                   \
        pl += 256;

#define CONSUME(xx)                                                       \
        asm volatile("s_waitcnt vmcnt(7)" ::: "memory");                  \
        __builtin_amdgcn_sched_barrier(0);                                \
        finish(xx, icur, po);                                             \
        po += 256; icur += 256;

        // prologue: fill 8 slots
        LOADV(x0) LOADV(x1) LOADV(x2) LOADV(x3)
        LOADV(x4_) LOADV(x5) LOADV(x6) LOADV(x7)

        const int trips = nppipe - 8;      // multiple of 8
        for (int t = 0; t < trips; t += 8) {
            CONSUME(x0) LOADV(x0)
            CONSUME(x1) LOADV(x1)
            CONSUME(x2) LOADV(x2)
            CONSUME(x3) LOADV(x3)
            CONSUME(x4_) LOADV(x4_)
            CONSUME(x5) LOADV(x5)
            CONSUME(x6) LOADV(x6)
            CONSUME(x7) LOADV(x7)
        }
        // drain
        CONSUME(x0) CONSUME(x1) CONSUME(x2) CONSUME(x3)
        CONSUME(x4_) CONSUME(x5) CONSUME(x6) CONSUME(x7)
#undef LOADV
#undef CONSUME
    } else {
        nppipe = 0;
    }

    // remainder vectors (plain compiler-managed path, <2% of work)
    for (int i = nppipe * 256 + tid; i < nvec; i += 256)
        finish(v4[i], i, o4 + i);

    // scalar tail
    for (int j = preN + (nvec << 2) + tid; j < V; j += 256) {
        float x = pg * vd[base + j];
        if ((bm[j >> 5] >> (j & 31)) & 1u) x += lookup(j);
        __builtin_nontemporal_store(x, &out[base + j]);
    }
}

// ---------------------------------------------------------------------------
// Fallback (round-1 fused kernel, verified correct) if ws/V/L out of bounds.
// ---------------------------------------------------------------------------
__global__ __launch_bounds__(256) void fused_fallback_kernel(
    const float* __restrict__ vocab_ds, const float* __restrict__ attns,
    const float* __restrict__ p_gens, const int* __restrict__ sources,
    float* __restrict__ out, int V, int L, int B)
{
    const int row = blockIdx.x;
    const int tid = threadIdx.x;
    const size_t base = (size_t)row * (size_t)V;
    const float pg = p_gens[row];

    const int mis  = (int)(base & 3);
    const int pre  = mis ? (4 - mis) : 0;
    const int preN = pre < V ? pre : V;
    for (int j = tid; j < preN; j += blockDim.x)
        out[base + j] = pg * vocab_ds[base + j];
    const int nvec = (V - preN) >> 2;
    const f32x4* __restrict__ v4 = (const f32x4*)(vocab_ds + base + preN);
    f32x4* __restrict__ o4       = (f32x4*)(out + base + preN);
    for (int i = tid; i < nvec; i += blockDim.x) {
        f32x4 x = v4[i];
        x *= pg;
        o4[i] = x;
    }
    for (int j = preN + (nvec << 2) + tid; j < V; j += blockDim.x)
        out[base + j] = pg * vocab_ds[base + j];

    __shared__ int s_src[512];
    const int b = row % B;
    const bool use_lds = (L <= 512);
    if (use_lds) {
        for (int l = tid; l < L; l += blockDim.x)
            s_src[l] = sources[(size_t)l * B + b];
    }
    __syncthreads();
    const float gate = 1.0f - pg;
    for (int l = tid; l < L; l += blockDim.x) {
        const int v = use_lds ? s_src[l] : sources[(size_t)l * B + b];
        if (v < 0 || v >= V) continue;
        bool last = true;
        for (int l2 = l + 1; l2 < L; ++l2) {
            const int v2 = use_lds ? s_src[l2] : sources[(size_t)l2 * B + b];
            if (v2 == v) { last = false; break; }
        }
        if (last) {
            const float a = gate * attns[(size_t)row * L + l];
            out[base + v] = pg * vocab_ds[base + v] + a;
        }
    }
}

extern "C" void kernel_launch(void* const* d_in, const int* in_sizes, int n_in,
                              void* d_out, int out_size, void* d_ws, size_t ws_size,
                              hipStream_t stream) {
    const float* vocab_ds = (const float*)d_in[0];
    const float* attns    = (const float*)d_in[1];
    const float* p_gens   = (const float*)d_in[2];
    const int*   sources  = (const int*)d_in[3];
    const int rows = in_sizes[2];
    const int V    = in_sizes[0] / rows;
    const int L    = in_sizes[1] / rows;
    const int B    = in_sizes[3] / L;
    float* out = (float*)d_out;

    const size_t need = (size_t)B * (size_t)L * 2 * sizeof(int);
    const bool fits = (ws_size >= need) && (V <= (NWMAX - 1) * 32) && (L <= LPAD);
    if (fits) {
        int* sv = (int*)d_ws;
        int* sl = sv + (size_t)B * (size_t)L;
        sort_kernel<<<B, 256, 0, stream>>>(sources, sv, sl, L, B, V);
        fused_kernel<<<rows, 256, 0, stream>>>(vocab_ds, attns, p_gens,
                                               sv, sl, out, V, L, B);
    } else {
        fused_fallback_kernel<<<rows, 256, 0, stream>>>(
            vocab_ds, attns, p_gens, sources, out, V, L, B);
    }
}